// Round 15
// baseline (54.869 us; speedup 1.0000x reference)
//
#include <hip/hip_runtime.h>
#include <stdint.h>

#define HH 512
#define WW 512
#define PLANE (HH*WW)
#define NCH 20
#define GRAV_PACK 0x1E9Du

// ---------------- no-drain workgroup barrier (LDS-only ordering) ----------------
__device__ __forceinline__ void bar_lds() {
    __builtin_amdgcn_sched_barrier(0);
    asm volatile("s_waitcnt lgkmcnt(0)" ::: "memory");
    __builtin_amdgcn_s_barrier();
    __builtin_amdgcn_sched_barrier(0);
}

// ---------------- nontemporal helpers (native clang vector type) ----------------
typedef float f32x4 __attribute__((ext_vector_type(4)));

__device__ __forceinline__ void st_nt(float* p, float4 v) {
    f32x4 w; w.x = v.x; w.y = v.y; w.z = v.z; w.w = v.w;
    __builtin_nontemporal_store(w, (f32x4*)p);
}
__device__ __forceinline__ float4 ld_nt(const float4* p) {
    f32x4 w = __builtin_nontemporal_load((const f32x4*)p);
    float4 v; v.x = w.x; v.y = w.y; v.z = w.z; v.w = w.w;
    return v;
}

// ---------------- SWAR helpers (per-byte lanes) ----------------
__device__ __forceinline__ uint32_t eqz4(uint32_t x) {
    uint32_t nz = (x | (x >> 1) | (x >> 2) | (x >> 3)) & 0x01010101u;
    return nz ^ 0x01010101u;
}
__device__ __forceinline__ uint32_t bmask(uint32_t b) {
    uint32_t h = b << 7;
    return (h - (h >> 7)) | h;
}

// ---------------- Kernel 1: pack eid|grav<<4|dens<<5 + fall-dir nibble ----------------
__device__ __forceinline__ uint32_t pack_cell(float d_,
                                              float c1_, float c5_, float c6_, float c8_,
                                              float c2_, float c9_, float c10_,
                                              float c3_, float c4_) {
    int d = (int)d_;
    int e;
    if (d == 4)      e = (c1_ != 0.f) ? 1 : (c5_ != 0.f) ? 5 : (c6_ != 0.f) ? 6 : (c8_ != 0.f) ? 8 : 13;
    else if (d == 3) e = (c2_ != 0.f) ? 2 : (c9_ != 0.f) ? 9 : (c10_ != 0.f) ? 10 : 12;
    else if (d == 2) e = (c3_ != 0.f) ? 3 : 11;
    else if (d == 1) e = 0;
    else             e = (c4_ != 0.f) ? 4 : 7;
    int g = (int)((GRAV_PACK >> e) & 1u);
    return (uint32_t)(e | (g << 4) | (d << 5));
}

__global__ __launch_bounds__(256) void extract_k(const float* __restrict__ world,
                                                 const float* __restrict__ rnd,
                                                 uint32_t* __restrict__ st,
                                                 uint8_t* __restrict__ fb) {
    int idx = blockIdx.x * 256 + threadIdx.x;      // 4 cells each
    int b  = idx >> 16;
    int p4 = idx & 0xFFFF;
    const float4* base = (const float4*)(world + (size_t)b * NCH * PLANE) + p4;
    float4 vD  = ld_nt(base + 14 * (PLANE / 4));
    float4 v1  = ld_nt(base +  1 * (PLANE / 4));
    float4 v5  = ld_nt(base +  5 * (PLANE / 4));
    float4 v6  = ld_nt(base +  6 * (PLANE / 4));
    float4 v8  = ld_nt(base +  8 * (PLANE / 4));
    float4 v2  = ld_nt(base +  2 * (PLANE / 4));
    float4 v9  = ld_nt(base +  9 * (PLANE / 4));
    float4 v10 = ld_nt(base + 10 * (PLANE / 4));
    float4 v3  = ld_nt(base +  3 * (PLANE / 4));
    float4 v4  = ld_nt(base +  4 * (PLANE / 4));
    float4 rv  = ld_nt((const float4*)(rnd + (size_t)b * PLANE) + p4);
    uint32_t b0 = pack_cell(vD.x, v1.x, v5.x, v6.x, v8.x, v2.x, v9.x, v10.x, v3.x, v4.x);
    uint32_t b1 = pack_cell(vD.y, v1.y, v5.y, v6.y, v8.y, v2.y, v9.y, v10.y, v3.y, v4.y);
    uint32_t b2 = pack_cell(vD.z, v1.z, v5.z, v6.z, v8.z, v2.z, v9.z, v10.z, v3.z, v4.z);
    uint32_t b3 = pack_cell(vD.w, v1.w, v5.w, v6.w, v8.w, v2.w, v9.w, v10.w, v3.w, v4.w);
    st[idx] = b0 | (b1 << 8) | (b2 << 16) | (b3 << 24);
    uint32_t nib = 0;
    nib |= (rv.x > 0.5f) ? 1u : 0u;
    nib |= (rv.y > 0.5f) ? 2u : 0u;
    nib |= (rv.z > 0.5f) ? 4u : 0u;
    nib |= (rv.w > 0.5f) ? 8u : 0u;
    fb[idx] = (uint8_t)nib;
}

// ---------------- Kernel 2: 2-tile pipelined SWAR sim, 512 threads ----------------
#define TILE_R 32
#define TILE_C 64
#define HALO_T 9
#define HALO_B 8
#define HALO_W 8                       // bytes; word-aligned halo
#define RH (TILE_R + HALO_T + HALO_B)  // 49 rows
#define RWW 20                         // words per row (80 bytes)
#define RWS 21                         // LDS row stride in words
#define NW (RH*RWW)                    // 980 words
#define NT 512
#define NOWN 2                         // ceil(NW/NT)

__global__ __launch_bounds__(NT, 4) void sim_k(const uint8_t* __restrict__ st_in,
                                               const uint8_t* __restrict__ fb,
                                               float* __restrict__ out) {
    __shared__ uint32_t bufA[RH * RWS];
    __shared__ uint32_t bufB[RH * RWS];
    __shared__ uint32_t aux [RH * RWS];   // per byte: bit0 fall_dir, bit1 did_gravity

    const int tid = threadIdx.x;
    const int h0  = blockIdx.y * TILE_R;
    const int w0  = blockIdx.x * TILE_C;

    uint32_t sreg[NOWN], freg[NOWN], dgreg[NOWN];

    // ---- stage: global -> bufA + registers; fall_dir from nibble grid ----
    auto stage = [&](const uint8_t* stb, const uint8_t* fbb) {
#pragma unroll
        for (int k = 0; k < NOWN; ++k) {
            int r = tid + k * NT;
            if (r < NW) {
                int i = r / RWW, jw = r - i * RWW;
                int gh  = (h0 + i - HALO_T) & (HH - 1);
                int gwb = (w0 + jw * 4 - HALO_W) & (WW - 1);
                uint32_t w = *(const uint32_t*)(stb + gh * WW + gwb);
                bufA[i * RWS + jw] = w;
                sreg[k] = w;
                uint32_t nib = fbb[gh * (WW / 4) + (gwb >> 2)];
                freg[k] = (nib * 0x00204081u) & 0x01010101u;   // spread 4 bits to bytes
                dgreg[k] = 0u;
            }
        }
    };

    // ---- 9 passes; pass0: bufA->bufB, ping-pong; final state in bufB ----
    auto passes = [&]() {
        // pass 0: stone support / gravity rewrite (zero-padded at global edges)
#pragma unroll
        for (int k = 0; k < NOWN; ++k) {
            int r = tid + k * NT;
            if (r < NW) {
                int i = r / RWW, jw = r - i * RWW;
                uint32_t s = sreg[k];
                uint32_t stm = eqz4((s & 0x0F0F0F0Fu) ^ 0x09090909u);
                int im = (i > 0) ? i - 1 : 0;
                int jl = (jw > 0) ? jw - 1 : 0;
                int jr = (jw < RWW - 1) ? jw + 1 : RWW - 1;
                uint32_t wU  = bufA[im * RWS + jw];
                uint32_t wUL = bufA[im * RWS + jl];
                uint32_t wUR = bufA[im * RWS + jr];
                uint32_t upL = (wU << 8) | (wUL >> 24);
                uint32_t upR = (wU >> 8) | (wUR << 24);
                uint32_t stL = eqz4((upL & 0x0F0F0F0Fu) ^ 0x09090909u);
                uint32_t stR = eqz4((upR & 0x0F0F0F0Fu) ^ 0x09090909u);
                int gh  = (h0 + i - HALO_T) & (HH - 1);
                int gwb = (w0 + jw * 4 - HALO_W) & (WW - 1);
                uint32_t rowOK = (gh != 0) ? 0x01010101u : 0u;
                uint32_t okL = 0x01010101u ^ ((gwb == 0)      ? 0x00000001u : 0u);
                uint32_t okR = 0x01010101u ^ ((gwb == WW - 4) ? 0x01000000u : 0u);
                uint32_t supL = stL & okL & rowOK;
                uint32_t supR = stR & okR & rowOK;
                uint32_t g2 = 0x01010101u ^ (supL & supR);
                uint32_t ns = (s & ~0x10101010u) | (g2 << 4);
                uint32_t res = s ^ ((s ^ ns) & bmask(stm));
                bufB[i * RWS + jw] = res;
                sreg[k] = res;
            }
        }
        bar_lds();

        uint32_t* cur = bufB;
        uint32_t* nxt = bufA;

        // passes 1..4: vertical gravity (did_gravity kept in registers)
#pragma unroll
        for (int curr = 0; curr < 4; ++curr) {
            const uint32_t crep = (uint32_t)curr * 0x01010101u;
            const uint32_t CKP7 = crep + 0x0F0F0F0Fu;   // const-a gtb
#pragma unroll
            for (int k = 0; k < NOWN; ++k) {
                int r = tid + k * NT;
                if (r < NW) {
                    int i = r / RWW, jw = r - i * RWW;
                    int ia = (i > 0) ? i - 1 : 0;
                    int ib = (i < RH - 1) ? i + 1 : RH - 1;
                    uint32_t s  = sreg[k];
                    uint32_t sa = cur[ia * RWS + jw];
                    uint32_t sb = cur[ib * RWS + jw];
                    uint32_t d  = (s  >> 5) & 0x07070707u;
                    uint32_t da = (sa >> 5) & 0x07070707u;
                    uint32_t db = (sb >> 5) & 0x07070707u;
                    uint32_t g  = (s  >> 4) & 0x01010101u;
                    uint32_t ga = (sa >> 4) & 0x01010101u;
                    uint32_t gb = (sb >> 4) & 0x01010101u;
                    uint32_t bel = eqz4(d ^ crep)  & (((CKP7 - db) & 0x10101010u) >> 4) & gb & g;
                    uint32_t abv = eqz4(da ^ crep) & (((CKP7 - d)  & 0x10101010u) >> 4) & ga & g;
                    uint32_t res = s ^ ((s ^ sb) & bmask(bel)) ^ ((s ^ sa) & bmask(abv));
                    nxt[i * RWS + jw] = res;
                    sreg[k] = res;
                    dgreg[k] |= abv;
                    if (curr == 3)   // merged aux write, covered by this phase's barrier
                        aux[i * RWS + jw] = freg[k] | (dgreg[k] << 1);
                }
            }
            bar_lds();
            uint32_t* t = cur; cur = nxt; nxt = t;
        }

        // ---- precompute aux neighbor combos ONCE (aux frozen after pass 4) ----
        uint32_t ablL[NOWN], aarL[NOWN], ablR[NOWN], aarR[NOWN];
#pragma unroll
        for (int k = 0; k < NOWN; ++k) {
            int r = tid + k * NT;
            if (r < NW) {
                int i = r / RWW, jw = r - i * RWW;
                int ia = (i > 0) ? i - 1 : 0;
                int ib = (i < RH - 1) ? i + 1 : RH - 1;
                int jl = (jw > 0) ? jw - 1 : 0;
                int jr = (jw < RWW - 1) ? jw + 1 : RWW - 1;
                uint32_t aB  = aux[ib * RWS + jw];
                uint32_t aA  = aux[ia * RWS + jw];
                uint32_t aBL = aux[ib * RWS + jl];
                uint32_t aBR = aux[ib * RWS + jr];
                uint32_t aAL = aux[ia * RWS + jl];
                uint32_t aAR = aux[ia * RWS + jr];
                ablL[k] = (aB << 8) | (aBL >> 24);
                aarL[k] = (aA >> 8) | (aAR << 24);
                ablR[k] = (aB >> 8) | (aBR << 24);
                aarR[k] = (aA << 8) | (aAL >> 24);
            }
        }

        // passes 5..8: diagonal falls (elem,dir) = (2,L),(2,R),(12,L),(12,R)
        // dens(2) == dens(12) == 3 -> const-a gtb with K = 0x12 per byte
#pragma unroll
        for (int pass = 0; pass < 4; ++pass) {
            const int  elem = (pass < 2) ? 2 : 12;
            const bool fl   = ((pass & 1) == 0);
            const uint32_t erep = (uint32_t)elem * 0x01010101u;
#pragma unroll
            for (int k = 0; k < NOWN; ++k) {
                int r = tid + k * NT;
                if (r < NW) {
                    int i = r / RWW, jw = r - i * RWW;
                    int ia = (i > 0) ? i - 1 : 0;
                    int ib = (i < RH - 1) ? i + 1 : RH - 1;
                    int jl = (jw > 0) ? jw - 1 : 0;
                    int jr = (jw < RWW - 1) ? jw + 1 : RWW - 1;
                    uint32_t s  = sreg[k];
                    uint32_t wB = cur[ib * RWS + jw];
                    uint32_t wA = cur[ia * RWS + jw];
                    uint32_t sbl, sar;
                    uint32_t abl, aar;
                    if (fl) {
                        uint32_t wBL = cur[ib * RWS + jl], wAR = cur[ia * RWS + jr];
                        sbl = (wB << 8) | (wBL >> 24);
                        sar = (wA >> 8) | (wAR << 24);
                        abl = ablL[k];
                        aar = aarL[k];
                    } else {
                        uint32_t wBR = cur[ib * RWS + jr], wAL = cur[ia * RWS + jl];
                        sbl = (wB >> 8) | (wBR << 24);
                        sar = (wA << 8) | (wAL >> 24);
                        abl = ablR[k];
                        aar = aarR[k];
                    }
                    uint32_t d   = (s   >> 5) & 0x07070707u;
                    uint32_t dbl = (sbl >> 5) & 0x07070707u;
                    uint32_t g   = (s   >> 4) & 0x01010101u;
                    uint32_t gbl = (sbl >> 4) & 0x01010101u;
                    uint32_t gar = (sar >> 4) & 0x01010101u;
                    uint32_t ndg   = dgreg[k] ^ 0x01010101u;
                    uint32_t ndgbl = ((~abl) >> 1) & 0x01010101u;
                    uint32_t ndgar = ((~aar) >> 1) & 0x01010101u;
                    uint32_t mtc = (fl ? freg[k] : ~freg[k]) & 0x01010101u;
                    uint32_t mta = (fl ? aar : ~aar) & 0x01010101u;
                    uint32_t eqe  = eqz4((s   & 0x0F0F0F0Fu) ^ erep);
                    uint32_t eqer = eqz4((sar & 0x0F0F0F0Fu) ^ erep);
                    uint32_t bbl = eqe  & ndgbl & ndg & mtc & (((0x12121212u - dbl) & 0x10101010u) >> 4) & gbl & g;
                    uint32_t bar = eqer & ndgar & ndg & mta & (((0x12121212u - d)   & 0x10101010u) >> 4) & gar & g;
                    uint32_t res = s ^ ((s ^ sbl) & bmask(bbl)) ^ ((s ^ sar) & bmask(bar));
                    nxt[i * RWS + jw] = res;
                    sreg[k] = res;
                }
            }
            bar_lds();
            uint32_t* t = cur; cur = nxt; nxt = t;
        }
        // 9 writes: B,A,B,A,B,A,B,A,B -> final state in bufB
    };

    // ---- expand own core word to channels 0-15 (16-19 zeroed at entry), NT stores ----
    auto expand = [&](float* ob, uint32_t w) {
        float* base = ob + (size_t)(h0 + (tid >> 4)) * WW + (w0 + (tid & 15) * 4);
        uint32_t oh0 = 1u << ( w        & 15u);
        uint32_t oh1 = 1u << ((w >>  8) & 15u);
        uint32_t oh2 = 1u << ((w >> 16) & 15u);
        uint32_t oh3 = 1u << ((w >> 24) & 15u);
#pragma unroll
        for (int c = 0; c < 14; ++c) {
            float4 v;
            v.x = (float)((oh0 >> c) & 1u);
            v.y = (float)((oh1 >> c) & 1u);
            v.z = (float)((oh2 >> c) & 1u);
            v.w = (float)((oh3 >> c) & 1u);
            st_nt(base + (size_t)c * PLANE, v);
        }
        float4 vd = { (float)((w >>  5) & 7u), (float)((w >> 13) & 7u),
                      (float)((w >> 21) & 7u), (float)((w >> 29) & 7u) };
        st_nt(base + (size_t)14 * PLANE, vd);
        float4 vg = { (float)((w >>  4) & 1u), (float)((w >> 12) & 1u),
                      (float)((w >> 20) & 1u), (float)((w >> 28) & 1u) };
        st_nt(base + (size_t)15 * PLANE, vg);
    };

    // ---- 2-tile pipeline: batches z and z+4 ----
    const int bA = blockIdx.z, bB = blockIdx.z + 4;
    const uint8_t* stA = st_in + (size_t)bA * PLANE;
    const uint8_t* stB = st_in + (size_t)bB * PLANE;
    const uint8_t* fbA = fb + (size_t)bA * (PLANE / 4);
    const uint8_t* fbB = fb + (size_t)bB * (PLANE / 4);
    float* obA = out + (size_t)bA * NCH * PLANE;
    float* obB = out + (size_t)bB * NCH * PLANE;

    // early zero-channel stores for BOTH tiles: drain under all pass phases
    {
        float4 z = {0.f, 0.f, 0.f, 0.f};
        float* baseA = obA + (size_t)(h0 + (tid >> 4)) * WW + (w0 + (tid & 15) * 4);
        float* baseB = obB + (size_t)(h0 + (tid >> 4)) * WW + (w0 + (tid & 15) * 4);
#pragma unroll
        for (int c = 16; c < 20; ++c) {
            st_nt(baseA + (size_t)c * PLANE, z);
            st_nt(baseB + (size_t)c * PLANE, z);
        }
    }

    const int coreIdx = (HALO_T + (tid >> 4)) * RWS + (HALO_W / 4) + (tid & 15);

    stage(stA, fbA);
    bar_lds();
    passes();                               // tile A -> bufB

    uint32_t wA = bufB[coreIdx];            // own core word (post-barrier, safe)
    stage(stB, fbB);                        // loads issue BEFORE expand's stores
    expand(obA, wA);                        // stores drain under tile-B passes
    bar_lds();
    passes();                               // tile B -> bufB

    expand(obB, bufB[coreIdx]);
}

extern "C" void kernel_launch(void* const* d_in, const int* in_sizes, int n_in,
                              void* d_out, int out_size, void* d_ws, size_t ws_size,
                              hipStream_t stream) {
    const float* world = (const float*)d_in[0];
    const float* rnd   = (const float*)d_in[1];
    float* out = (float*)d_out;
    uint32_t* st = (uint32_t*)d_ws;                          // 2 MB packed byte grid
    uint8_t*  fb = (uint8_t*)d_ws + 2 * 1024 * 1024;         // 512 KB fall-dir nibbles

    extract_k<<<2048, 256, 0, stream>>>(world, rnd, st, fb);

    dim3 grid(WW / TILE_C, HH / TILE_R, 4);   // 512 blocks, 2 tiles each
    sim_k<<<grid, NT, 0, stream>>>((const uint8_t*)st, fb, out);
}

// Round 16
// 53.448 us; speedup vs baseline: 1.0266x; 1.0266x over previous
//
#include <hip/hip_runtime.h>
#include <stdint.h>

#define HH 512
#define WW 512
#define PLANE (HH*WW)
#define NCH 20
#define GRAV_PACK 0x1E9Du

// ---------------- no-drain workgroup barrier (LDS-only ordering) ----------------
__device__ __forceinline__ void bar_lds() {
    __builtin_amdgcn_sched_barrier(0);
    asm volatile("s_waitcnt lgkmcnt(0)" ::: "memory");
    __builtin_amdgcn_s_barrier();
    __builtin_amdgcn_sched_barrier(0);
}

// ---------------- SWAR helpers (per-byte lanes) ----------------
__device__ __forceinline__ uint32_t eqz4(uint32_t x) {
    uint32_t nz = (x | (x >> 1) | (x >> 2) | (x >> 3)) & 0x01010101u;
    return nz ^ 0x01010101u;
}
__device__ __forceinline__ uint32_t bmask(uint32_t b) {
    uint32_t h = b << 7;
    return (h - (h >> 7)) | h;
}

// ---------------- Kernel 1: pack eid|grav<<4|dens<<5 + fall-dir nibble ----------------
__device__ __forceinline__ uint32_t pack_cell(float d_,
                                              float c1_, float c5_, float c6_, float c8_,
                                              float c2_, float c9_, float c10_,
                                              float c3_, float c4_) {
    int d = (int)d_;
    int e;
    if (d == 4)      e = (c1_ != 0.f) ? 1 : (c5_ != 0.f) ? 5 : (c6_ != 0.f) ? 6 : (c8_ != 0.f) ? 8 : 13;
    else if (d == 3) e = (c2_ != 0.f) ? 2 : (c9_ != 0.f) ? 9 : (c10_ != 0.f) ? 10 : 12;
    else if (d == 2) e = (c3_ != 0.f) ? 3 : 11;
    else if (d == 1) e = 0;
    else             e = (c4_ != 0.f) ? 4 : 7;
    int g = (int)((GRAV_PACK >> e) & 1u);
    return (uint32_t)(e | (g << 4) | (d << 5));
}

__global__ __launch_bounds__(256) void extract_k(const float* __restrict__ world,
                                                 const float* __restrict__ rnd,
                                                 uint32_t* __restrict__ st,
                                                 uint8_t* __restrict__ fb) {
    int idx = blockIdx.x * 256 + threadIdx.x;      // 4 cells each
    int b  = idx >> 16;
    int p4 = idx & 0xFFFF;
    const float4* base = (const float4*)(world + (size_t)b * NCH * PLANE) + p4;
    float4 vD  = base[14 * (PLANE / 4)];
    float4 v1  = base[ 1 * (PLANE / 4)];
    float4 v5  = base[ 5 * (PLANE / 4)];
    float4 v6  = base[ 6 * (PLANE / 4)];
    float4 v8  = base[ 8 * (PLANE / 4)];
    float4 v2  = base[ 2 * (PLANE / 4)];
    float4 v9  = base[ 9 * (PLANE / 4)];
    float4 v10 = base[10 * (PLANE / 4)];
    float4 v3  = base[ 3 * (PLANE / 4)];
    float4 v4  = base[ 4 * (PLANE / 4)];
    float4 rv  = *((const float4*)(rnd + (size_t)b * PLANE) + p4);
    uint32_t b0 = pack_cell(vD.x, v1.x, v5.x, v6.x, v8.x, v2.x, v9.x, v10.x, v3.x, v4.x);
    uint32_t b1 = pack_cell(vD.y, v1.y, v5.y, v6.y, v8.y, v2.y, v9.y, v10.y, v3.y, v4.y);
    uint32_t b2 = pack_cell(vD.z, v1.z, v5.z, v6.z, v8.z, v2.z, v9.z, v10.z, v3.z, v4.z);
    uint32_t b3 = pack_cell(vD.w, v1.w, v5.w, v6.w, v8.w, v2.w, v9.w, v10.w, v3.w, v4.w);
    st[idx] = b0 | (b1 << 8) | (b2 << 16) | (b3 << 24);
    uint32_t nib = 0;
    nib |= (rv.x > 0.5f) ? 1u : 0u;
    nib |= (rv.y > 0.5f) ? 2u : 0u;
    nib |= (rv.z > 0.5f) ? 4u : 0u;
    nib |= (rv.w > 0.5f) ? 8u : 0u;
    fb[idx] = (uint8_t)nib;
}

// ---------------- Kernel 2: 2-tile pipelined SWAR sim, 512 threads ----------------
#define TILE_R 32
#define TILE_C 64
#define HALO_T 9
#define HALO_B 8
#define HALO_W 8                       // bytes; word-aligned halo
#define RH (TILE_R + HALO_T + HALO_B)  // 49 rows
#define RWW 20                         // words per row (80 bytes)
#define RWS 21                         // LDS row stride in words
#define NW (RH*RWW)                    // 980 words
#define NT 512
#define NOWN 2                         // ceil(NW/NT)

__global__ __launch_bounds__(NT, 4) void sim_k(const uint8_t* __restrict__ st_in,
                                               const uint8_t* __restrict__ fb,
                                               float* __restrict__ out) {
    __shared__ uint32_t bufA[RH * RWS];
    __shared__ uint32_t bufB[RH * RWS];
    __shared__ uint32_t aux [RH * RWS];   // per byte: bit0 fall_dir, bit1 did_gravity

    const int tid = threadIdx.x;
    const int h0  = blockIdx.y * TILE_R;
    const int w0  = blockIdx.x * TILE_C;

    uint32_t sreg[NOWN], freg[NOWN], dgreg[NOWN];

    // ---- stage: global -> bufA + registers; fall_dir from nibble grid ----
    auto stage = [&](const uint8_t* stb, const uint8_t* fbb) {
#pragma unroll
        for (int k = 0; k < NOWN; ++k) {
            int r = tid + k * NT;
            if (r < NW) {
                int i = r / RWW, jw = r - i * RWW;
                int gh  = (h0 + i - HALO_T) & (HH - 1);
                int gwb = (w0 + jw * 4 - HALO_W) & (WW - 1);
                uint32_t w = *(const uint32_t*)(stb + gh * WW + gwb);
                bufA[i * RWS + jw] = w;
                sreg[k] = w;
                uint32_t nib = fbb[gh * (WW / 4) + (gwb >> 2)];
                freg[k] = (nib * 0x00204081u) & 0x01010101u;   // spread 4 bits to bytes
                dgreg[k] = 0u;
            }
        }
    };

    // ---- 9 passes; pass0: bufA->bufB, ping-pong; final state in bufB ----
    auto passes = [&]() {
        // pass 0: stone support / gravity rewrite (zero-padded at global edges)
#pragma unroll
        for (int k = 0; k < NOWN; ++k) {
            int r = tid + k * NT;
            if (r < NW) {
                int i = r / RWW, jw = r - i * RWW;
                uint32_t s = sreg[k];
                uint32_t stm = eqz4((s & 0x0F0F0F0Fu) ^ 0x09090909u);
                int im = (i > 0) ? i - 1 : 0;
                int jl = (jw > 0) ? jw - 1 : 0;
                int jr = (jw < RWW - 1) ? jw + 1 : RWW - 1;
                uint32_t wU  = bufA[im * RWS + jw];
                uint32_t wUL = bufA[im * RWS + jl];
                uint32_t wUR = bufA[im * RWS + jr];
                uint32_t upL = (wU << 8) | (wUL >> 24);
                uint32_t upR = (wU >> 8) | (wUR << 24);
                uint32_t stL = eqz4((upL & 0x0F0F0F0Fu) ^ 0x09090909u);
                uint32_t stR = eqz4((upR & 0x0F0F0F0Fu) ^ 0x09090909u);
                int gh  = (h0 + i - HALO_T) & (HH - 1);
                int gwb = (w0 + jw * 4 - HALO_W) & (WW - 1);
                uint32_t rowOK = (gh != 0) ? 0x01010101u : 0u;
                uint32_t okL = 0x01010101u ^ ((gwb == 0)      ? 0x00000001u : 0u);
                uint32_t okR = 0x01010101u ^ ((gwb == WW - 4) ? 0x01000000u : 0u);
                uint32_t supL = stL & okL & rowOK;
                uint32_t supR = stR & okR & rowOK;
                uint32_t g2 = 0x01010101u ^ (supL & supR);
                uint32_t ns = (s & ~0x10101010u) | (g2 << 4);
                uint32_t res = s ^ ((s ^ ns) & bmask(stm));
                bufB[i * RWS + jw] = res;
                sreg[k] = res;
            }
        }
        bar_lds();

        uint32_t* cur = bufB;
        uint32_t* nxt = bufA;

        // passes 1..4: vertical gravity (did_gravity kept in registers)
#pragma unroll
        for (int curr = 0; curr < 4; ++curr) {
            const uint32_t crep = (uint32_t)curr * 0x01010101u;
            const uint32_t CKP7 = crep + 0x0F0F0F0Fu;   // const-a gtb
#pragma unroll
            for (int k = 0; k < NOWN; ++k) {
                int r = tid + k * NT;
                if (r < NW) {
                    int i = r / RWW, jw = r - i * RWW;
                    int ia = (i > 0) ? i - 1 : 0;
                    int ib = (i < RH - 1) ? i + 1 : RH - 1;
                    uint32_t s  = sreg[k];
                    uint32_t sa = cur[ia * RWS + jw];
                    uint32_t sb = cur[ib * RWS + jw];
                    uint32_t d  = (s  >> 5) & 0x07070707u;
                    uint32_t da = (sa >> 5) & 0x07070707u;
                    uint32_t db = (sb >> 5) & 0x07070707u;
                    uint32_t g  = (s  >> 4) & 0x01010101u;
                    uint32_t ga = (sa >> 4) & 0x01010101u;
                    uint32_t gb = (sb >> 4) & 0x01010101u;
                    uint32_t bel = eqz4(d ^ crep)  & (((CKP7 - db) & 0x10101010u) >> 4) & gb & g;
                    uint32_t abv = eqz4(da ^ crep) & (((CKP7 - d)  & 0x10101010u) >> 4) & ga & g;
                    uint32_t res = s ^ ((s ^ sb) & bmask(bel)) ^ ((s ^ sa) & bmask(abv));
                    nxt[i * RWS + jw] = res;
                    sreg[k] = res;
                    dgreg[k] |= abv;
                    if (curr == 3)   // merged aux write, covered by this phase's barrier
                        aux[i * RWS + jw] = freg[k] | (dgreg[k] << 1);
                }
            }
            bar_lds();
            uint32_t* t = cur; cur = nxt; nxt = t;
        }

        // passes 5..8: diagonal falls (elem,dir) = (2,L),(2,R),(12,L),(12,R)
        // dens(2) == dens(12) == 3 -> const-a gtb with K = 0x12 per byte
#pragma unroll
        for (int pass = 0; pass < 4; ++pass) {
            const int  elem = (pass < 2) ? 2 : 12;
            const bool fl   = ((pass & 1) == 0);
            const uint32_t erep = (uint32_t)elem * 0x01010101u;
#pragma unroll
            for (int k = 0; k < NOWN; ++k) {
                int r = tid + k * NT;
                if (r < NW) {
                    int i = r / RWW, jw = r - i * RWW;
                    int ia = (i > 0) ? i - 1 : 0;
                    int ib = (i < RH - 1) ? i + 1 : RH - 1;
                    int jl = (jw > 0) ? jw - 1 : 0;
                    int jr = (jw < RWW - 1) ? jw + 1 : RWW - 1;
                    uint32_t s  = sreg[k];
                    uint32_t wB = cur[ib * RWS + jw];
                    uint32_t wA = cur[ia * RWS + jw];
                    uint32_t aB = aux[ib * RWS + jw];
                    uint32_t aA = aux[ia * RWS + jw];
                    uint32_t sbl, sar, abl, aar;
                    if (fl) {
                        uint32_t wBL = cur[ib * RWS + jl], wAR = cur[ia * RWS + jr];
                        uint32_t aBL = aux[ib * RWS + jl], aAR = aux[ia * RWS + jr];
                        sbl = (wB << 8) | (wBL >> 24);
                        sar = (wA >> 8) | (wAR << 24);
                        abl = (aB << 8) | (aBL >> 24);
                        aar = (aA >> 8) | (aAR << 24);
                    } else {
                        uint32_t wBR = cur[ib * RWS + jr], wAL = cur[ia * RWS + jl];
                        uint32_t aBR = aux[ib * RWS + jr], aAL = aux[ia * RWS + jl];
                        sbl = (wB >> 8) | (wBR << 24);
                        sar = (wA << 8) | (wAL >> 24);
                        abl = (aB >> 8) | (aBR << 24);
                        aar = (aA << 8) | (aAL >> 24);
                    }
                    uint32_t d   = (s   >> 5) & 0x07070707u;
                    uint32_t dbl = (sbl >> 5) & 0x07070707u;
                    uint32_t g   = (s   >> 4) & 0x01010101u;
                    uint32_t gbl = (sbl >> 4) & 0x01010101u;
                    uint32_t gar = (sar >> 4) & 0x01010101u;
                    uint32_t ndg   = dgreg[k] ^ 0x01010101u;
                    uint32_t ndgbl = ((~abl) >> 1) & 0x01010101u;
                    uint32_t ndgar = ((~aar) >> 1) & 0x01010101u;
                    uint32_t mtc = (fl ? freg[k] : ~freg[k]) & 0x01010101u;
                    uint32_t mta = (fl ? aar : ~aar) & 0x01010101u;
                    uint32_t eqe  = eqz4((s   & 0x0F0F0F0Fu) ^ erep);
                    uint32_t eqer = eqz4((sar & 0x0F0F0F0Fu) ^ erep);
                    uint32_t bbl = eqe  & ndgbl & ndg & mtc & (((0x12121212u - dbl) & 0x10101010u) >> 4) & gbl & g;
                    uint32_t bar = eqer & ndgar & ndg & mta & (((0x12121212u - d)   & 0x10101010u) >> 4) & gar & g;
                    uint32_t res = s ^ ((s ^ sbl) & bmask(bbl)) ^ ((s ^ sar) & bmask(bar));
                    nxt[i * RWS + jw] = res;
                    sreg[k] = res;
                }
            }
            bar_lds();
            uint32_t* t = cur; cur = nxt; nxt = t;
        }
        // 9 writes: B,A,B,A,B,A,B,A,B -> final state in bufB
    };

    // ---- expand own core word to channels 0-15 (16-19 zeroed at kernel entry) ----
    auto expand = [&](float* ob, uint32_t w) {
        float* base = ob + (size_t)(h0 + (tid >> 4)) * WW + (w0 + (tid & 15) * 4);
        uint32_t oh0 = 1u << ( w        & 15u);
        uint32_t oh1 = 1u << ((w >>  8) & 15u);
        uint32_t oh2 = 1u << ((w >> 16) & 15u);
        uint32_t oh3 = 1u << ((w >> 24) & 15u);
#pragma unroll
        for (int c = 0; c < 14; ++c) {
            float4 v;
            v.x = (float)((oh0 >> c) & 1u);
            v.y = (float)((oh1 >> c) & 1u);
            v.z = (float)((oh2 >> c) & 1u);
            v.w = (float)((oh3 >> c) & 1u);
            *(float4*)(base + (size_t)c * PLANE) = v;
        }
        float4 vd = { (float)((w >>  5) & 7u), (float)((w >> 13) & 7u),
                      (float)((w >> 21) & 7u), (float)((w >> 29) & 7u) };
        *(float4*)(base + (size_t)14 * PLANE) = vd;
        float4 vg = { (float)((w >>  4) & 1u), (float)((w >> 12) & 1u),
                      (float)((w >> 20) & 1u), (float)((w >> 28) & 1u) };
        *(float4*)(base + (size_t)15 * PLANE) = vg;
    };

    // ---- 2-tile pipeline: batches z and z+4 ----
    const int bA = blockIdx.z, bB = blockIdx.z + 4;
    const uint8_t* stA = st_in + (size_t)bA * PLANE;
    const uint8_t* stB = st_in + (size_t)bB * PLANE;
    const uint8_t* fbA = fb + (size_t)bA * (PLANE / 4);
    const uint8_t* fbB = fb + (size_t)bB * (PLANE / 4);
    float* obA = out + (size_t)bA * NCH * PLANE;
    float* obB = out + (size_t)bB * NCH * PLANE;

    // early zero-channel stores for BOTH tiles: drain under all pass phases
    {
        float4 z = {0.f, 0.f, 0.f, 0.f};
        float* baseA = obA + (size_t)(h0 + (tid >> 4)) * WW + (w0 + (tid & 15) * 4);
        float* baseB = obB + (size_t)(h0 + (tid >> 4)) * WW + (w0 + (tid & 15) * 4);
#pragma unroll
        for (int c = 16; c < 20; ++c) {
            *(float4*)(baseA + (size_t)c * PLANE) = z;
            *(float4*)(baseB + (size_t)c * PLANE) = z;
        }
    }

    const int coreIdx = (HALO_T + (tid >> 4)) * RWS + (HALO_W / 4) + (tid & 15);

    stage(stA, fbA);
    bar_lds();
    passes();                               // tile A -> bufB

    uint32_t wA = bufB[coreIdx];            // own core word (post-barrier, safe)
    stage(stB, fbB);                        // loads issue BEFORE expand's stores
    expand(obA, wA);                        // stores drain under tile-B passes
    bar_lds();
    passes();                               // tile B -> bufB

    expand(obB, bufB[coreIdx]);
}

extern "C" void kernel_launch(void* const* d_in, const int* in_sizes, int n_in,
                              void* d_out, int out_size, void* d_ws, size_t ws_size,
                              hipStream_t stream) {
    const float* world = (const float*)d_in[0];
    const float* rnd   = (const float*)d_in[1];
    float* out = (float*)d_out;
    uint32_t* st = (uint32_t*)d_ws;                          // 2 MB packed byte grid
    uint8_t*  fb = (uint8_t*)d_ws + 2 * 1024 * 1024;         // 512 KB fall-dir nibbles

    extract_k<<<2048, 256, 0, stream>>>(world, rnd, st, fb);

    dim3 grid(WW / TILE_C, HH / TILE_R, 4);   // 512 blocks, 2 tiles each
    sim_k<<<grid, NT, 0, stream>>>((const uint8_t*)st, fb, out);
}